// Round 8
// baseline (921.329 us; speedup 1.0000x reference)
//
#include <hip/hip_runtime.h>
#include <math.h>

#define VOCAB 32000
#define D_IN  256
#define D_H   32
#define B_SZ  16
#define S_LEN 512
#define NTOK  (B_SZ * S_LEN)   // 8192
#define NV1   16               // vocab splits in sum pass
#define VT1   (VOCAB / 16 / NV1)   // 125 tiles of 16 rows
#define NV2   25               // vocab splits in out pass
#define VT2   (VOCAB / 16 / NV2)   // 80 tiles

typedef __bf16 bf16;
typedef __attribute__((ext_vector_type(8))) __bf16 bf16x8;
typedef __attribute__((ext_vector_type(4))) float f32x4;
typedef __attribute__((ext_vector_type(2))) float f32x2;

__device__ __forceinline__ float sigf(float x) {
    return 1.0f / (1.0f + __expf(-x));
}

__device__ __forceinline__ float tanhfast(float x) {
    float ax = fabsf(x);
    float e = __expf(-2.0f * ax);
    float r = (1.0f - e) / (1.0f + e);
    return copysignf(r, x);
}

__device__ __forceinline__ float dot4(float4 a, float4 b) {
    return a.x * b.x + a.y * b.y + a.z * b.z + a.w * b.w;
}

// lane l <-> lane l^32 exchange via v_permlane32_swap_b32 (VALU, no LDS).
// convA resolves the HW swap-direction convention (probed at runtime).
__device__ __forceinline__ void xswap32(float a, bool convA, float& P, float& Q) {
    float x = a, y = a;
    asm volatile("v_permlane32_swap_b32 %0, %1" : "+v"(x), "+v"(y));
    P = convA ? y : x;
    Q = convA ? x : y;
}

// ---------------------------------------------------------------------------
// Convert W_fc (f32 [32000][32]) to bf16 hi/lo split arrays.
// ---------------------------------------------------------------------------
__global__ __launch_bounds__(256) void k_cvt_w(
    const float* __restrict__ W, bf16* __restrict__ Whi, bf16* __restrict__ Wlo)
{
    const long i = ((long)blockIdx.x * 256 + threadIdx.x) * 4;
    float4 w = *(const float4*)(W + i);
    bf16 h0 = (bf16)w.x, h1 = (bf16)w.y, h2 = (bf16)w.z, h3 = (bf16)w.w;
    bf16 l0 = (bf16)(w.x - (float)h0), l1 = (bf16)(w.y - (float)h1);
    bf16 l2 = (bf16)(w.z - (float)h2), l3 = (bf16)(w.w - (float)h3);
    typedef __attribute__((ext_vector_type(4))) __bf16 bf16x4;
    bf16x4 hv = {h0, h1, h2, h3}, lv = {l0, l1, l2, l3};
    *(bf16x4*)(Whi + i) = hv;
    *(bf16x4*)(Wlo + i) = lv;
}

// ---------------------------------------------------------------------------
// Kernel A: G1[t][g] = emb[x_ids[t]] . W_ih1[g] + (b_ih1[g] + b_hh1[g])
// ---------------------------------------------------------------------------
__global__ __launch_bounds__(128) void k_embed_gates(
    const int* __restrict__ x_ids, const float* __restrict__ emb,
    const float* __restrict__ W_ih1, const float* __restrict__ b_ih1,
    const float* __restrict__ b_hh1, float* __restrict__ G1)
{
    __shared__ float4 xs[4][64];
    const int tid = threadIdx.x;
    const int t0  = blockIdx.x * 4;
    const int r0  = tid >> 6, j = tid & 63;
    #pragma unroll
    for (int rr = 0; rr < 2; ++rr) {
        int r = rr * 2 + r0;
        long id = x_ids[t0 + r];
        xs[r][j] = ((const float4*)(emb + id * (long)D_IN))[j];
    }
    __syncthreads();

    const int g = tid;
    const float4* wrow = (const float4*)(W_ih1 + (long)g * D_IN);
    const float bias = b_ih1[g] + b_hh1[g];
    float a0 = bias, a1 = bias, a2 = bias, a3 = bias;
    #pragma unroll 8
    for (int jj = 0; jj < 64; ++jj) {
        float4 w = wrow[jj];
        a0 += dot4(w, xs[0][jj]);
        a1 += dot4(w, xs[1][jj]);
        a2 += dot4(w, xs[2][jj]);
        a3 += dot4(w, xs[3][jj]);
    }
    G1[(long)(t0 + 0) * 128 + g] = a0;
    G1[(long)(t0 + 1) * 128 + g] = a1;
    G1[(long)(t0 + 2) * 128 + g] = a2;
    G1[(long)(t0 + 3) * 128 + g] = a3;
}

// ---------------------------------------------------------------------------
// Kernel B: wave-synchronous 2-layer LSTM. One 64-lane wave per chain.
// Lane l owns gate rows l and 64+l (f32x2-paired). h broadcast is now via
// LDS same-address reads: lanes<32 ds_write_b32 h, then ALL lanes reload the
// 32-vector with 8x ds_read_b128 into lane-uniform VGPRs (replaces 96
// v_readlane/step -> no VALU->SGPR->VALU hazards). Layer-2's recurrent-half
// FMAs are scheduled between the h1 write and h1 read to hide LDS latency.
// ---------------------------------------------------------------------------
__global__ __launch_bounds__(64, 1) void k_lstm_wave(
    const float* __restrict__ G1,
    const float* __restrict__ W_hh1,
    const float* __restrict__ W_ih2, const float* __restrict__ W_hh2,
    const float* __restrict__ b_ih2, const float* __restrict__ b_hh2,
    bf16* __restrict__ Hhi, bf16* __restrict__ Hlo)
{
    const int l = threadIdx.x;
    const int b = blockIdx.x;
    const int ga = l, gb = 64 + l;

    __shared__ alignas(16) float hb1[32];
    __shared__ alignas(16) float hb2[32];

    // probe the permlane32_swap direction convention once
    int px = l, py = l;
    asm volatile("v_permlane32_swap_b32 %0, %1" : "+v"(px), "+v"(py));
    const bool convA = (__builtin_amdgcn_readfirstlane(px) == 32);

    // paired recurrent weights: {row_ga[j], row_gb[j]}
    f32x2 w1[32], wi2[32], wh2[32];
    #pragma unroll
    for (int j = 0; j < 32; ++j) {
        w1[j]  = (f32x2){ W_hh1[ga * D_H + j], W_hh1[gb * D_H + j] };
        wi2[j] = (f32x2){ W_ih2[ga * D_H + j], W_ih2[gb * D_H + j] };
        wh2[j] = (f32x2){ W_hh2[ga * D_H + j], W_hh2[gb * D_H + j] };
    }
    // PIN: opaque defs -> no rematerialization of the weight loads.
    #pragma unroll
    for (int j = 0; j < 32; ++j) {
        asm volatile("" : "+v"(w1[j]), "+v"(wi2[j]), "+v"(wh2[j]));
    }
    const float bias2a = b_ih2[ga] + b_hh2[ga];
    const float bias2b = b_ih2[gb] + b_hh2[gb];

    // lane-uniform copies of h1(t-1), h2(t-1)
    float h1r[32], h2r[32];
    #pragma unroll
    for (int j = 0; j < 32; ++j) { h1r[j] = 0.0f; h2r[j] = 0.0f; }
    float c1 = 0.0f, c2 = 0.0f;

    const float* g1base = G1 + (long)b * S_LEN * 128;
    float g1a = g1base[ga], g1b = g1base[gb];

    bf16* ghi = Hhi + (long)b * S_LEN * D_H;
    bf16* glo = Hlo + (long)b * S_LEN * D_H;

    #pragma unroll 1
    for (int s = 0; s < S_LEN; ++s) {
        // prefetch next step's layer-1 input gates
        float na = 0.0f, nb = 0.0f;
        if (s + 1 < S_LEN) {
            na = g1base[(s + 1) * 128 + ga];
            nb = g1base[(s + 1) * 128 + gb];
        }

        // ---- layer 1 (uses lane-uniform h1r = h1(t-1)) ----
        f32x2 A0 = {0.f, 0.f}, A1 = {0.f, 0.f}, A2 = {0.f, 0.f}, A3 = {0.f, 0.f};
        #pragma unroll
        for (int j = 0; j < 32; j += 4) {
            A0 += w1[j]     * (f32x2){h1r[j],     h1r[j]};
            A1 += w1[j + 1] * (f32x2){h1r[j + 1], h1r[j + 1]};
            A2 += w1[j + 2] * (f32x2){h1r[j + 2], h1r[j + 2]};
            A3 += w1[j + 3] * (f32x2){h1r[j + 3], h1r[j + 3]};
        }
        f32x2 As = (A0 + A1) + (A2 + A3);
        float accA = g1a + As.x;
        float accB = g1b + As.y;
        float aa = sigf(accA);                              // i (l<32) / f (l>=32)
        float ab = (l < 32) ? tanhfast(accB) : sigf(accB);  // g (l<32) / o (l>=32)
        float iv, fv, gv, ov;
        xswap32(aa, convA, iv, fv);
        xswap32(ab, convA, gv, ov);
        c1 = fv * c1 + iv * gv;          // lanes l and l+32 redundantly hold unit l&31
        float h1v = ov * tanhfast(c1);

        if (l < 32) hb1[l] = h1v;        // ds_write_b32 (unit l)

        // ---- layer-2 recurrent half (h2r regs) — fills the write->read gap
        f32x2 R0 = {0.f, 0.f}, R1 = {0.f, 0.f}, R2 = {0.f, 0.f}, R3 = {0.f, 0.f};
        #pragma unroll
        for (int j = 0; j < 32; j += 4) {
            R0 += wh2[j]     * (f32x2){h2r[j],     h2r[j]};
            R1 += wh2[j + 1] * (f32x2){h2r[j + 1], h2r[j + 1]};
            R2 += wh2[j + 2] * (f32x2){h2r[j + 2], h2r[j + 2]};
            R3 += wh2[j + 3] * (f32x2){h2r[j + 3], h2r[j + 3]};
        }

        // reload h1r: 8x ds_read_b128, same addr across lanes -> broadcast
        #pragma unroll
        for (int q = 0; q < 8; ++q) {
            float4 v = ((const float4*)hb1)[q];
            h1r[4*q]   = v.x; h1r[4*q+1] = v.y;
            h1r[4*q+2] = v.z; h1r[4*q+3] = v.w;
        }

        // ---- layer-2 input half ----
        #pragma unroll
        for (int j = 0; j < 32; j += 4) {
            R0 += wi2[j]     * (f32x2){h1r[j],     h1r[j]};
            R1 += wi2[j + 1] * (f32x2){h1r[j + 1], h1r[j + 1]};
            R2 += wi2[j + 2] * (f32x2){h1r[j + 2], h1r[j + 2]};
            R3 += wi2[j + 3] * (f32x2){h1r[j + 3], h1r[j + 3]};
        }
        f32x2 Rs = (R0 + R1) + (R2 + R3);
        float a2 = bias2a + Rs.x;
        float b2 = bias2b + Rs.y;
        aa = sigf(a2);
        ab = (l < 32) ? tanhfast(b2) : sigf(b2);
        xswap32(aa, convA, iv, fv);
        xswap32(ab, convA, gv, ov);
        c2 = fv * c2 + iv * gv;
        float h2v = ov * tanhfast(c2);

        if (l < 32) {
            hb2[l] = h2v;                // ds_write_b32 (unit l)
            bf16 hi = (bf16)h2v;
            ghi[s * D_H + l] = hi;
            glo[s * D_H + l] = (bf16)(h2v - (float)hi);
        }

        // reload h2r for next step (latency hidden by loop tail + G1 prefetch)
        #pragma unroll
        for (int q = 0; q < 8; ++q) {
            float4 v = ((const float4*)hb2)[q];
            h2r[4*q]   = v.x; h2r[4*q+1] = v.y;
            h2r[4*q+2] = v.z; h2r[4*q+3] = v.w;
        }

        g1a = na; g1b = nb;
    }
}

// ---------------------------------------------------------------------------
// Kernel C1 (MFMA): partial softmax denominators.
// Block = 4 waves; wave owns 32 tokens (2 A-tiles), scans a vocab chunk.
// logits = Ahi.Bhi + Alo.Bhi + Ahi.Blo  (f32 accum).
// ---------------------------------------------------------------------------
__global__ __launch_bounds__(256) void k_fc_sum(
    const bf16* __restrict__ Hhi, const bf16* __restrict__ Hlo,
    const bf16* __restrict__ Whi, const bf16* __restrict__ Wlo,
    const float* __restrict__ b_fc, float* __restrict__ partial)
{
    const int lane = threadIdx.x & 63;
    const int wid  = threadIdx.x >> 6;
    const int tg   = blockIdx.x / NV1;
    const int nv   = blockIdx.x % NV1;
    const int t0   = tg * 128 + wid * 32;
    const int lr   = lane & 15, lq = lane >> 4;

    const long arow0 = (long)(t0 + lr) * D_H + lq * 8;
    const long arow1 = arow0 + 16 * D_H;
    bf16x8 a0h = *(const bf16x8*)(Hhi + arow0);
    bf16x8 a0l = *(const bf16x8*)(Hlo + arow0);
    bf16x8 a1h = *(const bf16x8*)(Hhi + arow1);
    bf16x8 a1l = *(const bf16x8*)(Hlo + arow1);

    f32x4 acc0 = {0.f, 0.f, 0.f, 0.f}, acc1 = {0.f, 0.f, 0.f, 0.f};
    const f32x4 z = {0.f, 0.f, 0.f, 0.f};
    int v0 = nv * (VOCAB / NV1);
    for (int tile = 0; tile < VT1; ++tile, v0 += 16) {
        const long brow = (long)(v0 + lr) * D_H + lq * 8;
        bf16x8 bh = *(const bf16x8*)(Whi + brow);
        bf16x8 bl = *(const bf16x8*)(Wlo + brow);
        float bias = b_fc[v0 + lr];
        f32x4 d0 = __builtin_amdgcn_mfma_f32_16x16x32_bf16(a0h, bh, z, 0, 0, 0);
        d0 = __builtin_amdgcn_mfma_f32_16x16x32_bf16(a0l, bh, d0, 0, 0, 0);
        d0 = __builtin_amdgcn_mfma_f32_16x16x32_bf16(a0h, bl, d0, 0, 0, 0);
        f32x4 d1 = __builtin_amdgcn_mfma_f32_16x16x32_bf16(a1h, bh, z, 0, 0, 0);
        d1 = __builtin_amdgcn_mfma_f32_16x16x32_bf16(a1l, bh, d1, 0, 0, 0);
        d1 = __builtin_amdgcn_mfma_f32_16x16x32_bf16(a1h, bl, d1, 0, 0, 0);
        #pragma unroll
        for (int r = 0; r < 4; ++r) {
            acc0[r] += __expf(d0[r] + bias);
            acc1[r] += __expf(d1[r] + bias);
        }
    }

    // reduce over the 16 vocab-lanes of each group
    #pragma unroll
    for (int m = 1; m < 16; m <<= 1) {
        #pragma unroll
        for (int r = 0; r < 4; ++r) {
            acc0[r] += __shfl_xor(acc0[r], m, 64);
            acc1[r] += __shfl_xor(acc1[r], m, 64);
        }
    }
    if (lr == 0) {
        #pragma unroll
        for (int r = 0; r < 4; ++r) {
            partial[(long)nv * NTOK + t0 + lq * 4 + r]      = acc0[r];
            partial[(long)nv * NTOK + t0 + 16 + lq * 4 + r] = acc1[r];
        }
    }
}

__global__ __launch_bounds__(256) void k_inv(
    const float* __restrict__ partial, float* __restrict__ inv_sum)
{
    const int t = blockIdx.x * 256 + threadIdx.x;
    float s = 0.0f;
    #pragma unroll
    for (int nv = 0; nv < NV1; ++nv) s += partial[(long)nv * NTOK + t];
    inv_sum[t] = 1.0f / s;
}

// ---------------------------------------------------------------------------
// Kernel C2 (MFMA): recompute logits, write normalized softmax.
// ---------------------------------------------------------------------------
__global__ __launch_bounds__(256) void k_fc_out(
    const bf16* __restrict__ Hhi, const bf16* __restrict__ Hlo,
    const bf16* __restrict__ Whi, const bf16* __restrict__ Wlo,
    const float* __restrict__ b_fc, const float* __restrict__ inv_sum,
    float* __restrict__ out)
{
    const int lane = threadIdx.x & 63;
    const int wid  = threadIdx.x >> 6;
    const int tg   = blockIdx.x / NV2;
    const int nv   = blockIdx.x % NV2;
    const int t0   = tg * 128 + wid * 32;
    const int lr   = lane & 15, lq = lane >> 4;

    const long arow0 = (long)(t0 + lr) * D_H + lq * 8;
    const long arow1 = arow0 + 16 * D_H;
    bf16x8 a0h = *(const bf16x8*)(Hhi + arow0);
    bf16x8 a0l = *(const bf16x8*)(Hlo + arow0);
    bf16x8 a1h = *(const bf16x8*)(Hhi + arow1);
    bf16x8 a1l = *(const bf16x8*)(Hlo + arow1);

    float inv0[4], inv1[4];
    #pragma unroll
    for (int r = 0; r < 4; ++r) {
        inv0[r] = inv_sum[t0 + lq * 4 + r];
        inv1[r] = inv_sum[t0 + 16 + lq * 4 + r];
    }

    const f32x4 z = {0.f, 0.f, 0.f, 0.f};
    int v0 = nv * (VOCAB / NV2);
    for (int tile = 0; tile < VT2; ++tile, v0 += 16) {
        const long brow = (long)(v0 + lr) * D_H + lq * 8;
        bf16x8 bh = *(const bf16x8*)(Whi + brow);
        bf16x8 bl = *(const bf16x8*)(Wlo + brow);
        float bias = b_fc[v0 + lr];
        f32x4 d0 = __builtin_amdgcn_mfma_f32_16x16x32_bf16(a0h, bh, z, 0, 0, 0);
        d0 = __builtin_amdgcn_mfma_f32_16x16x32_bf16(a0l, bh, d0, 0, 0, 0);
        d0 = __builtin_amdgcn_mfma_f32_16x16x32_bf16(a0h, bl, d0, 0, 0, 0);
        f32x4 d1 = __builtin_amdgcn_mfma_f32_16x16x32_bf16(a1h, bh, z, 0, 0, 0);
        d1 = __builtin_amdgcn_mfma_f32_16x16x32_bf16(a1l, bh, d1, 0, 0, 0);
        d1 = __builtin_amdgcn_mfma_f32_16x16x32_bf16(a1h, bl, d1, 0, 0, 0);
        const int vcol = v0 + lr;
        #pragma unroll
        for (int r = 0; r < 4; ++r) {
            out[(long)(t0 + lq * 4 + r) * VOCAB + vcol] =
                __expf(d0[r] + bias) * inv0[r];
            out[(long)(t0 + 16 + lq * 4 + r) * VOCAB + vcol] =
                __expf(d1[r] + bias) * inv1[r];
        }
    }
}

// ---------------------------------------------------------------------------
extern "C" void kernel_launch(void* const* d_in, const int* in_sizes, int n_in,
                              void* d_out, int out_size, void* d_ws, size_t ws_size,
                              hipStream_t stream)
{
    const int*   x_ids = (const int*)d_in[0];
    const float* emb   = (const float*)d_in[1];
    const float* W_ih1 = (const float*)d_in[2];
    const float* W_hh1 = (const float*)d_in[3];
    const float* b_ih1 = (const float*)d_in[4];
    const float* b_hh1 = (const float*)d_in[5];
    const float* W_ih2 = (const float*)d_in[6];
    const float* W_hh2 = (const float*)d_in[7];
    const float* b_ih2 = (const float*)d_in[8];
    const float* b_hh2 = (const float*)d_in[9];
    const float* W_fc  = (const float*)d_in[10];
    const float* b_fc  = (const float*)d_in[11];
    float* out = (float*)d_out;

    // workspace layout (bytes): keep 16B alignment everywhere
    char* p = (char*)d_ws;
    float* G1      = (float*)p;            p += (long)NTOK * 128 * 4;   // 4 MB
    bf16* Hhi      = (bf16*)p;             p += (long)NTOK * D_H * 2;   // 512 KB
    bf16* Hlo      = (bf16*)p;             p += (long)NTOK * D_H * 2;   // 512 KB
    bf16* Whi      = (bf16*)p;             p += (long)VOCAB * D_H * 2;  // 2 MB
    bf16* Wlo      = (bf16*)p;             p += (long)VOCAB * D_H * 2;  // 2 MB
    float* partial = (float*)p;            p += (long)NV1 * NTOK * 4;   // 512 KB
    float* inv_sum = (float*)p;            p += (long)NTOK * 4;         // 32 KB

    k_cvt_w<<<VOCAB * D_H / (256 * 4), 256, 0, stream>>>(W_fc, Whi, Wlo);
    k_embed_gates<<<NTOK / 4, 128, 0, stream>>>(x_ids, emb, W_ih1, b_ih1, b_hh1, G1);
    k_lstm_wave<<<B_SZ, 64, 0, stream>>>(G1, W_hh1, W_ih2, W_hh2, b_ih2, b_hh2, Hhi, Hlo);
    k_fc_sum<<<(NTOK / 128) * NV1, 256, 0, stream>>>(Hhi, Hlo, Whi, Wlo, b_fc, partial);
    k_inv<<<NTOK / 256, 256, 0, stream>>>(partial, inv_sum);
    k_fc_out<<<(NTOK / 128) * NV2, 256, 0, stream>>>(Hhi, Hlo, Whi, Wlo, b_fc, inv_sum, out);
}

// Round 11
// 862.732 us; speedup vs baseline: 1.0679x; 1.0679x over previous
//
#include <hip/hip_runtime.h>
#include <math.h>

#define VOCAB 32000
#define D_IN  256
#define D_H   32
#define B_SZ  16
#define S_LEN 512
#define NTOK  (B_SZ * S_LEN)   // 8192
#define NV1   16               // vocab splits in sum pass
#define VT1   (VOCAB / 16 / NV1)   // 125 tiles of 16 rows
#define NV2   25               // vocab splits in out pass
#define VT2   (VOCAB / 16 / NV2)   // 80 tiles
#define SG    (S_LEN / 4)      // 128 step-groups
#define SGP   (SG + 1)         // padded (last group = zeros)

typedef __bf16 bf16;
typedef __attribute__((ext_vector_type(8))) __bf16 bf16x8;
typedef __attribute__((ext_vector_type(4))) __bf16 bf16x4;
typedef __attribute__((ext_vector_type(4))) float f32x4;
typedef __attribute__((ext_vector_type(2))) float f32x2;

__device__ __forceinline__ float sigf(float x) {
    return 1.0f / (1.0f + __expf(-x));
}

__device__ __forceinline__ float tanhfast(float x) {
    float ax = fabsf(x);
    float e = __expf(-2.0f * ax);
    float r = (1.0f - e) / (1.0f + e);
    return copysignf(r, x);
}

__device__ __forceinline__ float dot4(float4 a, float4 b) {
    return a.x * b.x + a.y * b.y + a.z * b.z + a.w * b.w;
}

// broadcast lane j's value of v to all lanes via v_readlane (j compile-time)
__device__ __forceinline__ float rl(float v, int j) {
    return __builtin_bit_cast(float, __builtin_amdgcn_readlane(__builtin_bit_cast(int, v), j));
}

// lane l <-> lane l^32 exchange via v_permlane32_swap_b32 (VALU, no LDS).
__device__ __forceinline__ void xswap32(float a, bool convA, float& P, float& Q) {
    float x = a, y = a;
    asm volatile("v_permlane32_swap_b32 %0, %1" : "+v"(x), "+v"(y));
    P = convA ? y : x;
    Q = convA ? x : y;
}

// ---------------------------------------------------------------------------
// Convert W_fc (f32 [32000][32]) to bf16 hi/lo split arrays.
// ---------------------------------------------------------------------------
__global__ __launch_bounds__(256) void k_cvt_w(
    const float* __restrict__ W, bf16* __restrict__ Whi, bf16* __restrict__ Wlo)
{
    const long i = ((long)blockIdx.x * 256 + threadIdx.x) * 4;
    float4 w = *(const float4*)(W + i);
    bf16 h0 = (bf16)w.x, h1 = (bf16)w.y, h2 = (bf16)w.z, h3 = (bf16)w.w;
    bf16 l0 = (bf16)(w.x - (float)h0), l1 = (bf16)(w.y - (float)h1);
    bf16 l2 = (bf16)(w.z - (float)h2), l3 = (bf16)(w.w - (float)h3);
    bf16x4 hv = {h0, h1, h2, h3}, lv = {l0, l1, l2, l3};
    *(bf16x4*)(Whi + i) = hv;
    *(bf16x4*)(Wlo + i) = lv;
}

// ---------------------------------------------------------------------------
// Zero the padding step-group of G1p (group index SG for every [b][g]).
// ---------------------------------------------------------------------------
__global__ __launch_bounds__(256) void k_g1pad(float4* __restrict__ G1p)
{
    const int idx = blockIdx.x * 256 + threadIdx.x;   // 0 .. 2047
    G1p[((long)(idx >> 7) * 128 + (idx & 127)) * SGP + SG] = (float4){0.f, 0.f, 0.f, 0.f};
}

// ---------------------------------------------------------------------------
// Kernel A: input-side gates, packed by 4-step groups:
// G1p[b][g][sg] = float4 of gate g over steps 4*sg .. 4*sg+3.
// ---------------------------------------------------------------------------
__global__ __launch_bounds__(128) void k_embed_gates(
    const int* __restrict__ x_ids, const float* __restrict__ emb,
    const float* __restrict__ W_ih1, const float* __restrict__ b_ih1,
    const float* __restrict__ b_hh1, float4* __restrict__ G1p)
{
    __shared__ float4 xs[4][64];
    const int tid = threadIdx.x;
    const int t0  = blockIdx.x * 4;          // 4 consecutive tokens = same batch b
    const int r0  = tid >> 6, j = tid & 63;
    #pragma unroll
    for (int rr = 0; rr < 2; ++rr) {
        int r = rr * 2 + r0;
        long id = x_ids[t0 + r];
        xs[r][j] = ((const float4*)(emb + id * (long)D_IN))[j];
    }
    __syncthreads();

    const int g = tid;
    const float4* wrow = (const float4*)(W_ih1 + (long)g * D_IN);
    const float bias = b_ih1[g] + b_hh1[g];
    float a0 = bias, a1 = bias, a2 = bias, a3 = bias;
    #pragma unroll 8
    for (int jj = 0; jj < 64; ++jj) {
        float4 w = wrow[jj];
        a0 += dot4(w, xs[0][jj]);
        a1 += dot4(w, xs[1][jj]);
        a2 += dot4(w, xs[2][jj]);
        a3 += dot4(w, xs[3][jj]);
    }
    const int b  = t0 >> 9;          // t0 / 512
    const int sg = (t0 & 511) >> 2;  // (t0 % 512) / 4
    G1p[((long)b * 128 + g) * SGP + sg] = (float4){a0, a1, a2, a3};
}

// ---------------------------------------------------------------------------
// Kernel B: wave-synchronous 2-layer LSTM, ZERO per-step global memory.
// G1 loaded as float4 per 4 steps (cur/nxt rotation -> >=4 steps of load
// slack, no conditional). h2 trace buffered in LDS, flushed at the end.
// Broadcast via v_readlane; gate exchange via permlane32_swap.
// ---------------------------------------------------------------------------
__global__ __launch_bounds__(64, 1) void k_lstm_wave(
    const float4* __restrict__ G1p,
    const float* __restrict__ W_hh1,
    const float* __restrict__ W_ih2, const float* __restrict__ W_hh2,
    const float* __restrict__ b_ih2, const float* __restrict__ b_hh2,
    bf16* __restrict__ Hhi, bf16* __restrict__ Hlo)
{
    const int l = threadIdx.x;
    const int b = blockIdx.x;
    const int ga = l, gb = 64 + l;

    __shared__ alignas(16) float hstore[S_LEN * D_H];   // 64 KB h2 trace

    // probe the permlane32_swap direction convention once
    int px = l, py = l;
    asm volatile("v_permlane32_swap_b32 %0, %1" : "+v"(px), "+v"(py));
    const bool convA = (__builtin_amdgcn_readfirstlane(px) == 32);

    // paired recurrent weights: {row_ga[j], row_gb[j]}
    f32x2 w1[32], wi2[32], wh2[32];
    #pragma unroll
    for (int j = 0; j < 32; ++j) {
        w1[j]  = (f32x2){ W_hh1[ga * D_H + j], W_hh1[gb * D_H + j] };
        wi2[j] = (f32x2){ W_ih2[ga * D_H + j], W_ih2[gb * D_H + j] };
        wh2[j] = (f32x2){ W_hh2[ga * D_H + j], W_hh2[gb * D_H + j] };
    }
    #pragma unroll
    for (int j = 0; j < 32; ++j) {
        asm volatile("" : "+v"(w1[j]), "+v"(wi2[j]), "+v"(wh2[j]));
    }
    const float bias2a = b_ih2[ga] + b_hh2[ga];
    const float bias2b = b_ih2[gb] + b_hh2[gb];

    const float4* rowA = G1p + ((long)b * 128 + ga) * SGP;
    const float4* rowB = G1p + ((long)b * 128 + gb) * SGP;
    float4 curA = rowA[0], curB = rowB[0];

    float h1v = 0.0f, h2v = 0.0f, c1 = 0.0f, c2 = 0.0f;

    #pragma unroll 1
    for (int sg = 0; sg < SG; ++sg) {
        // unconditional prefetch of the NEXT 4-step group (used 4 steps later)
        float4 nxtA = rowA[sg + 1];
        float4 nxtB = rowB[sg + 1];

        #pragma unroll
        for (int k = 0; k < 4; ++k) {
            const int s = sg * 4 + k;
            const float g1a = (k == 0) ? curA.x : (k == 1) ? curA.y
                            : (k == 2) ? curA.z : curA.w;
            const float g1b = (k == 0) ? curB.x : (k == 1) ? curB.y
                            : (k == 2) ? curB.z : curB.w;

            // ---- layer-2 recurrent half (depends only on h2(t-1)) ----
            f32x2 R0 = {0.f, 0.f}, R1 = {0.f, 0.f}, R2 = {0.f, 0.f}, R3 = {0.f, 0.f};
            #pragma unroll
            for (int j = 0; j < 32; j += 4) {
                R0 += wh2[j]     * rl(h2v, j);
                R1 += wh2[j + 1] * rl(h2v, j + 1);
                R2 += wh2[j + 2] * rl(h2v, j + 2);
                R3 += wh2[j + 3] * rl(h2v, j + 3);
            }

            // ---- layer 1 ----
            f32x2 A0 = {0.f, 0.f}, A1 = {0.f, 0.f}, A2 = {0.f, 0.f}, A3 = {0.f, 0.f};
            #pragma unroll
            for (int j = 0; j < 32; j += 4) {
                A0 += w1[j]     * rl(h1v, j);
                A1 += w1[j + 1] * rl(h1v, j + 1);
                A2 += w1[j + 2] * rl(h1v, j + 2);
                A3 += w1[j + 3] * rl(h1v, j + 3);
            }
            f32x2 As = (A0 + A1) + (A2 + A3);
            float accA = g1a + As.x;
            float accB = g1b + As.y;
            float aa = sigf(accA);                              // i / f
            float ab = (l < 32) ? tanhfast(accB) : sigf(accB);  // g / o
            float iv, fv, gv, ov;
            xswap32(aa, convA, iv, fv);
            xswap32(ab, convA, gv, ov);
            c1 = fv * c1 + iv * gv;
            h1v = ov * tanhfast(c1);

            // ---- layer-2 input half ----
            #pragma unroll
            for (int j = 0; j < 32; j += 4) {
                R0 += wi2[j]     * rl(h1v, j);
                R1 += wi2[j + 1] * rl(h1v, j + 1);
                R2 += wi2[j + 2] * rl(h1v, j + 2);
                R3 += wi2[j + 3] * rl(h1v, j + 3);
            }
            f32x2 Rs = (R0 + R1) + (R2 + R3);
            float a2 = bias2a + Rs.x;
            float b2 = bias2b + Rs.y;
            aa = sigf(a2);
            ab = (l < 32) ? tanhfast(b2) : sigf(b2);
            xswap32(aa, convA, iv, fv);
            xswap32(ab, convA, gv, ov);
            c2 = fv * c2 + iv * gv;
            h2v = ov * tanhfast(c2);

            if (l < 32) hstore[s * D_H + l] = h2v;   // LDS only, no global
        }
        curA = nxtA; curB = nxtB;
    }

    // ---- flush h2 trace: LDS -> bf16 hi/lo in global, vectorized ----
    bf16* ghi = Hhi + (long)b * S_LEN * D_H;
    bf16* glo = Hlo + (long)b * S_LEN * D_H;
    #pragma unroll 4
    for (int c = 0; c < (S_LEN * D_H) / 256; ++c) {
        const int i = c * 256 + l * 4;
        float4 v = *(const float4*)&hstore[i];
        bf16 h0 = (bf16)v.x, h1 = (bf16)v.y, h2 = (bf16)v.z, h3 = (bf16)v.w;
        bf16x4 hv = {h0, h1, h2, h3};
        bf16x4 lv = {(bf16)(v.x - (float)h0), (bf16)(v.y - (float)h1),
                     (bf16)(v.z - (float)h2), (bf16)(v.w - (float)h3)};
        *(bf16x4*)(ghi + i) = hv;
        *(bf16x4*)(glo + i) = lv;
    }
}

// ---------------------------------------------------------------------------
// Kernel C1 (MFMA): partial softmax denominators.
// ---------------------------------------------------------------------------
__global__ __launch_bounds__(256) void k_fc_sum(
    const bf16* __restrict__ Hhi, const bf16* __restrict__ Hlo,
    const bf16* __restrict__ Whi, const bf16* __restrict__ Wlo,
    const float* __restrict__ b_fc, float* __restrict__ partial)
{
    const int lane = threadIdx.x & 63;
    const int wid  = threadIdx.x >> 6;
    const int tg   = blockIdx.x / NV1;
    const int nv   = blockIdx.x % NV1;
    const int t0   = tg * 128 + wid * 32;
    const int lr   = lane & 15, lq = lane >> 4;

    const long arow0 = (long)(t0 + lr) * D_H + lq * 8;
    const long arow1 = arow0 + 16 * D_H;
    bf16x8 a0h = *(const bf16x8*)(Hhi + arow0);
    bf16x8 a0l = *(const bf16x8*)(Hlo + arow0);
    bf16x8 a1h = *(const bf16x8*)(Hhi + arow1);
    bf16x8 a1l = *(const bf16x8*)(Hlo + arow1);

    f32x4 acc0 = {0.f, 0.f, 0.f, 0.f}, acc1 = {0.f, 0.f, 0.f, 0.f};
    const f32x4 z = {0.f, 0.f, 0.f, 0.f};
    int v0 = nv * (VOCAB / NV1);
    for (int tile = 0; tile < VT1; ++tile, v0 += 16) {
        const long brow = (long)(v0 + lr) * D_H + lq * 8;
        bf16x8 bh = *(const bf16x8*)(Whi + brow);
        bf16x8 bl = *(const bf16x8*)(Wlo + brow);
        float bias = b_fc[v0 + lr];
        f32x4 d0 = __builtin_amdgcn_mfma_f32_16x16x32_bf16(a0h, bh, z, 0, 0, 0);
        d0 = __builtin_amdgcn_mfma_f32_16x16x32_bf16(a0l, bh, d0, 0, 0, 0);
        d0 = __builtin_amdgcn_mfma_f32_16x16x32_bf16(a0h, bl, d0, 0, 0, 0);
        f32x4 d1 = __builtin_amdgcn_mfma_f32_16x16x32_bf16(a1h, bh, z, 0, 0, 0);
        d1 = __builtin_amdgcn_mfma_f32_16x16x32_bf16(a1l, bh, d1, 0, 0, 0);
        d1 = __builtin_amdgcn_mfma_f32_16x16x32_bf16(a1h, bl, d1, 0, 0, 0);
        #pragma unroll
        for (int r = 0; r < 4; ++r) {
            acc0[r] += __expf(d0[r] + bias);
            acc1[r] += __expf(d1[r] + bias);
        }
    }

    #pragma unroll
    for (int m = 1; m < 16; m <<= 1) {
        #pragma unroll
        for (int r = 0; r < 4; ++r) {
            acc0[r] += __shfl_xor(acc0[r], m, 64);
            acc1[r] += __shfl_xor(acc1[r], m, 64);
        }
    }
    if (lr == 0) {
        #pragma unroll
        for (int r = 0; r < 4; ++r) {
            partial[(long)nv * NTOK + t0 + lq * 4 + r]      = acc0[r];
            partial[(long)nv * NTOK + t0 + 16 + lq * 4 + r] = acc1[r];
        }
    }
}

__global__ __launch_bounds__(256) void k_inv(
    const float* __restrict__ partial, float* __restrict__ inv_sum)
{
    const int t = blockIdx.x * 256 + threadIdx.x;
    float s = 0.0f;
    #pragma unroll
    for (int nv = 0; nv < NV1; ++nv) s += partial[(long)nv * NTOK + t];
    inv_sum[t] = 1.0f / s;
}

// ---------------------------------------------------------------------------
// Kernel C2 (MFMA): recompute logits, write normalized softmax.
// ---------------------------------------------------------------------------
__global__ __launch_bounds__(256) void k_fc_out(
    const bf16* __restrict__ Hhi, const bf16* __restrict__ Hlo,
    const bf16* __restrict__ Whi, const bf16* __restrict__ Wlo,
    const float* __restrict__ b_fc, const float* __restrict__ inv_sum,
    float* __restrict__ out)
{
    const int lane = threadIdx.x & 63;
    const int wid  = threadIdx.x >> 6;
    const int tg   = blockIdx.x / NV2;
    const int nv   = blockIdx.x % NV2;
    const int t0   = tg * 128 + wid * 32;
    const int lr   = lane & 15, lq = lane >> 4;

    const long arow0 = (long)(t0 + lr) * D_H + lq * 8;
    const long arow1 = arow0 + 16 * D_H;
    bf16x8 a0h = *(const bf16x8*)(Hhi + arow0);
    bf16x8 a0l = *(const bf16x8*)(Hlo + arow0);
    bf16x8 a1h = *(const bf16x8*)(Hhi + arow1);
    bf16x8 a1l = *(const bf16x8*)(Hlo + arow1);

    float inv0[4], inv1[4];
    #pragma unroll
    for (int r = 0; r < 4; ++r) {
        inv0[r] = inv_sum[t0 + lq * 4 + r];
        inv1[r] = inv_sum[t0 + 16 + lq * 4 + r];
    }

    const f32x4 z = {0.f, 0.f, 0.f, 0.f};
    int v0 = nv * (VOCAB / NV2);
    for (int tile = 0; tile < VT2; ++tile, v0 += 16) {
        const long brow = (long)(v0 + lr) * D_H + lq * 8;
        bf16x8 bh = *(const bf16x8*)(Whi + brow);
        bf16x8 bl = *(const bf16x8*)(Wlo + brow);
        float bias = b_fc[v0 + lr];
        f32x4 d0 = __builtin_amdgcn_mfma_f32_16x16x32_bf16(a0h, bh, z, 0, 0, 0);
        d0 = __builtin_amdgcn_mfma_f32_16x16x32_bf16(a0l, bh, d0, 0, 0, 0);
        d0 = __builtin_amdgcn_mfma_f32_16x16x32_bf16(a0h, bl, d0, 0, 0, 0);
        f32x4 d1 = __builtin_amdgcn_mfma_f32_16x16x32_bf16(a1h, bh, z, 0, 0, 0);
        d1 = __builtin_amdgcn_mfma_f32_16x16x32_bf16(a1l, bh, d1, 0, 0, 0);
        d1 = __builtin_amdgcn_mfma_f32_16x16x32_bf16(a1h, bl, d1, 0, 0, 0);
        const int vcol = v0 + lr;
        #pragma unroll
        for (int r = 0; r < 4; ++r) {
            out[(long)(t0 + lq * 4 + r) * VOCAB + vcol] =
                __expf(d0[r] + bias) * inv0[r];
            out[(long)(t0 + 16 + lq * 4 + r) * VOCAB + vcol] =
                __expf(d1[r] + bias) * inv1[r];
        }
    }
}

// ---------------------------------------------------------------------------
extern "C" void kernel_launch(void* const* d_in, const int* in_sizes, int n_in,
                              void* d_out, int out_size, void* d_ws, size_t ws_size,
                              hipStream_t stream)
{
    const int*   x_ids = (const int*)d_in[0];
    const float* emb   = (const float*)d_in[1];
    const float* W_ih1 = (const float*)d_in[2];
    const float* W_hh1 = (const float*)d_in[3];
    const float* b_ih1 = (const float*)d_in[4];
    const float* b_hh1 = (const float*)d_in[5];
    const float* W_ih2 = (const float*)d_in[6];
    const float* W_hh2 = (const float*)d_in[7];
    const float* b_ih2 = (const float*)d_in[8];
    const float* b_hh2 = (const float*)d_in[9];
    const float* W_fc  = (const float*)d_in[10];
    const float* b_fc  = (const float*)d_in[11];
    float* out = (float*)d_out;

    // workspace layout (bytes): keep 16B alignment everywhere
    char* p = (char*)d_ws;
    float4* G1p    = (float4*)p;           p += (long)B_SZ * 128 * SGP * 16; // ~4.2 MB
    bf16* Hhi      = (bf16*)p;             p += (long)NTOK * D_H * 2;   // 512 KB
    bf16* Hlo      = (bf16*)p;             p += (long)NTOK * D_H * 2;   // 512 KB
    bf16* Whi      = (bf16*)p;             p += (long)VOCAB * D_H * 2;  // 2 MB
    bf16* Wlo      = (bf16*)p;             p += (long)VOCAB * D_H * 2;  // 2 MB
    float* partial = (float*)p;            p += (long)NV1 * NTOK * 4;   // 512 KB
    float* inv_sum = (float*)p;            p += (long)NTOK * 4;         // 32 KB

    k_cvt_w<<<VOCAB * D_H / (256 * 4), 256, 0, stream>>>(W_fc, Whi, Wlo);
    k_g1pad<<<8, 256, 0, stream>>>(G1p);
    k_embed_gates<<<NTOK / 4, 128, 0, stream>>>(x_ids, emb, W_ih1, b_ih1, b_hh1, G1p);
    k_lstm_wave<<<B_SZ, 64, 0, stream>>>(G1p, W_hh1, W_ih2, W_hh2, b_ih2, b_hh2, Hhi, Hlo);
    k_fc_sum<<<(NTOK / 128) * NV1, 256, 0, stream>>>(Hhi, Hlo, Whi, Wlo, b_fc, partial);
    k_inv<<<NTOK / 256, 256, 0, stream>>>(partial, inv_sum);
    k_fc_out<<<(NTOK / 128) * NV2, 256, 0, stream>>>(Hhi, Hlo, Whi, Wlo, b_fc, inv_sum, out);
}